// Round 1
// baseline (825.630 us; speedup 1.0000x reference)
//
#include <hip/hip_runtime.h>
#include <math.h>

#define B_   16
#define V_   16
#define C_   64
#define M_   32
#define CM_  16
#define D_   128
#define OUT_ 600
#define NSEQ 256      // B*V
#define NROW 8192     // B*V*M

// ---- workspace layout (floats) ----
constexpr int OFF_VIS   = 0;                              // [3][256][128]
constexpr int OFF_MON   = OFF_VIS   + 3*NSEQ*D_;          // [2][8192][128]
constexpr int OFF_W12   = OFF_MON   + 2*NROW*D_;          // [2][4][2][128][128]
constexpr int OFF_WIHTM = OFF_W12   + 2*4*2*D_*D_;        // [5][128][384]
constexpr int OFF_WIHTV = OFF_WIHTM + 5*D_*384;           // [4][128][384]
constexpr int OFF_XE    = OFF_WIHTV + 4*D_*384;           // [2][256][128]
constexpr int OFF_GNN   = OFF_XE    + 2*NSEQ*D_;          // [8][8192][128]
constexpr int OFF_GI    = OFF_GNN   + 8*NROW*D_;          // [8][8192][384]
constexpr int OFF_LAST  = OFF_GI    + 8*NROW*384;         // [8][256][128]
constexpr int OFF_VGI   = OFF_LAST  + 8*NSEQ*D_;          // [10][256][384]
constexpr int OFF_VH    = OFF_VGI   + 10*NSEQ*384;        // [10][16][128]

// =====================================================================
// prep: combined GNN weights, transposed Wih (monitor+visit), weight/age xe
// =====================================================================
__global__ __launch_bounds__(256) void k_prep(
    const float* __restrict__ Wself, const float* __restrict__ Wmsg,
    const float* __restrict__ mWih,  const float* __restrict__ vWih,
    const float* __restrict__ wgt,   const float* __restrict__ age,
    const float* __restrict__ fwW,   const float* __restrict__ fwB,
    const float* __restrict__ faW,   const float* __restrict__ faB,
    float* __restrict__ w12, float* __restrict__ wihTm,
    float* __restrict__ wihTv, float* __restrict__ xe)
{
  int bx = blockIdx.x, tid = threadIdx.x;
  if (bx < 512) {                       // W1 = Wself - Wmsg/3 ; W2 = Wmsg/3
    int lin = bx*256 + tid;             // < 131072
    int pt = lin >> 14, rem = lin & 16383;
    float wsv = Wself[pt*16384 + rem];
    float wmv = Wmsg [pt*16384 + rem];
    w12[(pt*2+0)*16384 + rem] = wsv - wmv*(1.f/3.f);
    w12[(pt*2+1)*16384 + rem] = wmv*(1.f/3.f);
  } else if (bx < 1472) {               // mgru Wih transpose [g][k][j]
    int lin = (bx-512)*256 + tid;       // < 245760
    int g = lin / 49152, rem = lin % 49152;
    int k = rem / 384, j = rem % 384;
    wihTm[lin] = mWih[g*49152 + j*128 + k];
  } else if (bx < 2240) {               // vgru Wih transpose
    int lin = (bx-1472)*256 + tid;      // < 196608
    int g = lin / 49152, rem = lin % 49152;
    int k = rem / 384, j = rem % 384;
    wihTv[lin] = vWih[g*49152 + j*128 + k];
  } else {                              // xe for weight / age
    int lin = (bx-2240)*256 + tid;      // < 65536
    int which = lin >> 15, rem = lin & 32767;
    int n = rem >> 7, d = rem & 127;
    float x  = which ? age[n] : wgt[n];
    float Wv = which ? faW[d] : fwW[d];
    float bb = which ? faB[d] : fwB[d];
    xe[lin] = (x != 0.0f) ? (x*Wv + bb) : 0.0f;
  }
}

// =====================================================================
// visit-event embedding sum pools: vis[type][bv][d]
// =====================================================================
__global__ __launch_bounds__(128) void k_vis(
    const int* __restrict__ cc, const int* __restrict__ cp, const int* __restrict__ cd,
    const float* __restrict__ ec, const float* __restrict__ ep, const float* __restrict__ ed,
    float* __restrict__ vis)
{
  int type = blockIdx.x >> 8;
  int bv   = blockIdx.x & 255;
  int d    = threadIdx.x;
  const int*   codes = (type==0) ? cc : (type==1) ? cp : cd;
  const float* emb   = (type==0) ? ec : (type==1) ? ep : ed;
  float acc = 0.f;
  for (int c = 0; c < C_; ++c) {
    int code = codes[bv*C_ + c];
    acc += emb[code*D_ + d];
  }
  vis[(type*NSEQ + bv)*D_ + d] = acc;
}

// =====================================================================
// monitor-event pools: mon[p][bvm][d] = sum_c ei[ci]*ev[cv]
// =====================================================================
__global__ __launch_bounds__(128) void k_mon(
    const int* __restrict__ cli, const int* __restrict__ clv,
    const int* __restrict__ cii, const int* __restrict__ civ,
    const float* __restrict__ eli, const float* __restrict__ elv,
    const float* __restrict__ eii, const float* __restrict__ eiv,
    float* __restrict__ mon)
{
  int p   = blockIdx.x >> 13;
  int bvm = blockIdx.x & 8191;
  int d   = threadIdx.x;
  const int* ci = p ? cii : cli;  const int* cv = p ? civ : clv;
  const float* ei = p ? eii : eli; const float* ev = p ? eiv : elv;
  float acc = 0.f;
  #pragma unroll
  for (int c = 0; c < CM_; ++c) {
    int iv = ci[bvm*CM_ + c];
    int vv = cv[bvm*CM_ + c];
    acc += ei[iv*D_ + d] * ev[vv*D_ + d];
  }
  mon[(p*NROW + bvm)*D_ + d] = acc;
}

// =====================================================================
// GNN: out[pt] = relu( feat@W1 + total@W2 )  as one K=256 GEMM
// tile: 128 rows x 128 cols, 256 threads, 8x8 per thread
// =====================================================================
__global__ __launch_bounds__(256) void k_gnn(
    const float* __restrict__ vis, const float* __restrict__ mon,
    const float* __restrict__ w12, float* __restrict__ out)
{
  int pt   = blockIdx.x >> 6;
  int mblk = blockIdx.x & 63;
  int p = pt >> 2, t = pt & 3;
  int m0 = mblk * 128;
  int tid = threadIdx.x;
  __shared__ __align__(16) float Xs[32][132];
  __shared__ __align__(16) float Ws[32][132];
  float acc[8][8];
  #pragma unroll
  for (int i = 0; i < 8; ++i)
    #pragma unroll
    for (int jj = 0; jj < 8; ++jj) acc[i][jj] = 0.f;

  int tc = tid & 15, tr = tid >> 4;
  int kkS = tid & 31, rrS = tid >> 5;
  int cS  = tid & 127, kwS = tid >> 7;

  const float* monp = mon + p*NROW*D_;
  const float* visA = vis;
  const float* visB = vis + NSEQ*D_;
  const float* visC = vis + 2*NSEQ*D_;
  const float* featv = (t > 0) ? (vis + (t-1)*NSEQ*D_) : monp;

  for (int ks = 0; ks < 8; ++ks) {
    #pragma unroll
    for (int pass = 0; pass < 16; ++pass) {
      int r = rrS + pass*8;
      int row = m0 + r;
      int bv = row >> 5;
      int k = ks*32 + kkS;
      float v;
      if (k < 128) {
        v = (t == 0) ? monp[row*D_ + k] : featv[bv*D_ + k];
      } else {
        int k2 = k - 128;
        v = monp[row*D_ + k2] + visA[bv*D_ + k2] + visB[bv*D_ + k2] + visC[bv*D_ + k2];
      }
      Xs[kkS][r] = v;
    }
    #pragma unroll
    for (int pass = 0; pass < 16; ++pass) {
      int kk = kwS + pass*2;
      int k = ks*32 + kk;
      int which = (k >= 128) ? 1 : 0;
      Ws[kk][cS] = w12[((pt*2 + which)*128 + (k & 127))*128 + cS];
    }
    __syncthreads();
    #pragma unroll
    for (int kk = 0; kk < 32; ++kk) {
      float4 a0 = *(const float4*)&Xs[kk][tr*4];
      float4 a1 = *(const float4*)&Xs[kk][64 + tr*4];
      float4 b0 = *(const float4*)&Ws[kk][tc*4];
      float4 b1 = *(const float4*)&Ws[kk][64 + tc*4];
      float av[8] = {a0.x,a0.y,a0.z,a0.w,a1.x,a1.y,a1.z,a1.w};
      float bw[8] = {b0.x,b0.y,b0.z,b0.w,b1.x,b1.y,b1.z,b1.w};
      #pragma unroll
      for (int i = 0; i < 8; ++i)
        #pragma unroll
        for (int jj = 0; jj < 8; ++jj)
          acc[i][jj] += av[i]*bw[jj];
    }
    __syncthreads();
  }
  float* op = out + pt*NROW*D_;
  #pragma unroll
  for (int i = 0; i < 8; ++i) {
    int ri = (i < 4) ? (tr*4 + i) : (64 + tr*4 + i - 4);
    float4 v0 = make_float4(fmaxf(acc[i][0],0.f), fmaxf(acc[i][1],0.f),
                            fmaxf(acc[i][2],0.f), fmaxf(acc[i][3],0.f));
    float4 v1 = make_float4(fmaxf(acc[i][4],0.f), fmaxf(acc[i][5],0.f),
                            fmaxf(acc[i][6],0.f), fmaxf(acc[i][7],0.f));
    *(float4*)&op[(m0+ri)*D_ + tc*4] = v0;
    *(float4*)&op[(m0+ri)*D_ + 64 + tc*4] = v1;
  }
}

// =====================================================================
// gi precompute: gi[run][row][j] = gnn_out[run] @ WihT[g] + bih[g]
// =====================================================================
__global__ __launch_bounds__(256) void k_gi(
    const float* __restrict__ gnn, const float* __restrict__ wihTm,
    const float* __restrict__ mbih, float* __restrict__ gi)
{
  int bx = blockIdx.x;
  int run = bx / 192, rem = bx % 192;
  int mblk = rem / 3, nblk = rem % 3;
  int g = (run % 4 == 0) ? (run / 4) : (run % 4 + 1);
  int m0 = mblk * 128;
  int tid = threadIdx.x;
  __shared__ __align__(16) float Xs[32][132];
  __shared__ __align__(16) float Ws[32][132];
  float acc[8][8];
  #pragma unroll
  for (int i = 0; i < 8; ++i)
    #pragma unroll
    for (int jj = 0; jj < 8; ++jj) acc[i][jj] = 0.f;

  int tc = tid & 15, tr = tid >> 4;
  int kkS = tid & 31, rrS = tid >> 5;
  int cS  = tid & 127, kwS = tid >> 7;

  const float* X = gnn + run*NROW*D_;
  const float* W = wihTm + g*49152 + nblk*128;

  for (int ks = 0; ks < 4; ++ks) {
    #pragma unroll
    for (int pass = 0; pass < 16; ++pass) {
      int r = rrS + pass*8;
      Xs[kkS][r] = X[(m0 + r)*D_ + ks*32 + kkS];
    }
    #pragma unroll
    for (int pass = 0; pass < 16; ++pass) {
      int kk = kwS + pass*2;
      Ws[kk][cS] = W[(ks*32 + kk)*384 + cS];
    }
    __syncthreads();
    #pragma unroll
    for (int kk = 0; kk < 32; ++kk) {
      float4 a0 = *(const float4*)&Xs[kk][tr*4];
      float4 a1 = *(const float4*)&Xs[kk][64 + tr*4];
      float4 b0 = *(const float4*)&Ws[kk][tc*4];
      float4 b1 = *(const float4*)&Ws[kk][64 + tc*4];
      float av[8] = {a0.x,a0.y,a0.z,a0.w,a1.x,a1.y,a1.z,a1.w};
      float bw[8] = {b0.x,b0.y,b0.z,b0.w,b1.x,b1.y,b1.z,b1.w};
      #pragma unroll
      for (int i = 0; i < 8; ++i)
        #pragma unroll
        for (int jj = 0; jj < 8; ++jj)
          acc[i][jj] += av[i]*bw[jj];
    }
    __syncthreads();
  }
  const float* bb = mbih + g*384 + nblk*128;
  float4 bb0 = *(const float4*)&bb[tc*4];
  float4 bb1 = *(const float4*)&bb[64 + tc*4];
  #pragma unroll
  for (int i = 0; i < 8; ++i) {
    int ri = (i < 4) ? (tr*4 + i) : (64 + tr*4 + i - 4);
    float* rowp = gi + (run*NROW + m0 + ri)*384 + nblk*128;
    float4 v0 = make_float4(acc[i][0]+bb0.x, acc[i][1]+bb0.y, acc[i][2]+bb0.z, acc[i][3]+bb0.w);
    float4 v1 = make_float4(acc[i][4]+bb1.x, acc[i][5]+bb1.y, acc[i][6]+bb1.z, acc[i][7]+bb1.w);
    *(float4*)&rowp[tc*4] = v0;
    *(float4*)&rowp[64 + tc*4] = v1;
  }
}

// =====================================================================
// monitor-level GRU: 8 runs x 256 seqs, T=32. block = (run, 8-seq group),
// 384 threads, Whh row register-resident per thread.
// =====================================================================
__global__ __launch_bounds__(384) void k_mgru(
    const float* __restrict__ gi, const float* __restrict__ mWhh,
    const float* __restrict__ mbhh, float* __restrict__ last)
{
  int run = blockIdx.x >> 5, grp = blockIdx.x & 31;
  int j = threadIdx.x;
  int g = (run % 4 == 0) ? (run / 4) : (run % 4 + 1);
  float w[128];
  const float4* wrow = (const float4*)(mWhh + (g*384 + j)*128);
  #pragma unroll
  for (int k4 = 0; k4 < 32; ++k4) {
    float4 tt = wrow[k4];
    w[4*k4] = tt.x; w[4*k4+1] = tt.y; w[4*k4+2] = tt.z; w[4*k4+3] = tt.w;
  }
  float bj = mbhh[g*384 + j];
  __shared__ __align__(16) float hs[8][128];
  __shared__ float ghs[8][384];
  for (int idx = j; idx < 1024; idx += 384) hs[idx >> 7][idx & 127] = 0.f;
  __syncthreads();
  const float* gib = gi + (run*NROW + grp*256)*384;
  #pragma unroll 1
  for (int m = 0; m < 32; ++m) {
    #pragma unroll
    for (int s = 0; s < 8; ++s) {
      float acc = bj;
      if (j < 256) acc += gib[(s*32 + m)*384 + j];
      const float4* h4 = (const float4*)hs[s];
      #pragma unroll
      for (int k4 = 0; k4 < 32; ++k4) {
        float4 hv = h4[k4];
        acc += w[4*k4]*hv.x + w[4*k4+1]*hv.y + w[4*k4+2]*hv.z + w[4*k4+3]*hv.w;
      }
      ghs[s][j] = acc;
    }
    __syncthreads();
    if (j < 128) {
      #pragma unroll
      for (int s = 0; s < 8; ++s) {
        float r = 1.f/(1.f + __expf(-ghs[s][j]));
        float z = 1.f/(1.f + __expf(-ghs[s][j+128]));
        float gin = gib[(s*32 + m)*384 + 256 + j];
        float n = tanhf(gin + r*ghs[s][j+256]);
        hs[s][j] = (1.f - z)*n + z*hs[s][j];
      }
    }
    __syncthreads();
  }
  if (j < 128) {
    #pragma unroll
    for (int s = 0; s < 8; ++s)
      last[(run*NSEQ + grp*8 + s)*D_ + j] = hs[s][j];
  }
}

// =====================================================================
// visit-level gi precompute (small GEMM), 10 runs x 256 rows
// =====================================================================
__global__ __launch_bounds__(384) void k_vgi(
    const float* __restrict__ last, const float* __restrict__ xe,
    const float* __restrict__ wihTv, const float* __restrict__ vbih,
    float* __restrict__ vgi)
{
  int run = blockIdx.x >> 5;
  int rblk = blockIdx.x & 31;
  int j = threadIdx.x;
  int vidx = (run < 4) ? 0 : (run < 8) ? 1 : (run - 6);
  __shared__ float Xs[8][128];
  const float* X = (run < 8) ? (last + run*NSEQ*D_) : (xe + (run-8)*NSEQ*D_);
  for (int idx = j; idx < 1024; idx += 384) {
    int s = idx >> 7, k = idx & 127;
    Xs[s][k] = X[(rblk*8 + s)*D_ + k];
  }
  __syncthreads();
  float acc[8];
  float bias = vbih[vidx*384 + j];
  #pragma unroll
  for (int s = 0; s < 8; ++s) acc[s] = bias;
  const float* W = wihTv + vidx*49152 + j;
  #pragma unroll 4
  for (int k = 0; k < 128; ++k) {
    float wv = W[k*384];
    #pragma unroll
    for (int s = 0; s < 8; ++s) acc[s] += Xs[s][k] * wv;
  }
  #pragma unroll
  for (int s = 0; s < 8; ++s)
    vgi[(run*NSEQ + rblk*8 + s)*384 + j] = acc[s];
}

// =====================================================================
// visit-level GRU: 10 runs x 16 batch seqs, T=16. block = (run, b).
// =====================================================================
__global__ __launch_bounds__(384) void k_vgru(
    const float* __restrict__ vgi, const float* __restrict__ vWhh,
    const float* __restrict__ vbhh, float* __restrict__ vh)
{
  int run = blockIdx.x >> 4, b = blockIdx.x & 15;
  int j = threadIdx.x;
  int vidx = (run < 4) ? 0 : (run < 8) ? 1 : (run - 6);
  float w[128];
  const float4* wrow = (const float4*)(vWhh + (vidx*384 + j)*128);
  #pragma unroll
  for (int k4 = 0; k4 < 32; ++k4) {
    float4 tt = wrow[k4];
    w[4*k4] = tt.x; w[4*k4+1] = tt.y; w[4*k4+2] = tt.z; w[4*k4+3] = tt.w;
  }
  float bj = vbhh[vidx*384 + j];
  __shared__ __align__(16) float hsv[128];
  __shared__ float gh[384];
  if (j < 128) hsv[j] = 0.f;
  __syncthreads();
  const float* gib = vgi + (run*NSEQ + b*16)*384;
  #pragma unroll 1
  for (int v = 0; v < 16; ++v) {
    float acc = bj;
    if (j < 256) acc += gib[v*384 + j];
    const float4* h4 = (const float4*)hsv;
    #pragma unroll
    for (int k4 = 0; k4 < 32; ++k4) {
      float4 hv = h4[k4];
      acc += w[4*k4]*hv.x + w[4*k4+1]*hv.y + w[4*k4+2]*hv.z + w[4*k4+3]*hv.w;
    }
    gh[j] = acc;
    __syncthreads();
    if (j < 128) {
      float r = 1.f/(1.f + __expf(-gh[j]));
      float z = 1.f/(1.f + __expf(-gh[j+128]));
      float gin = gib[v*384 + 256 + j];
      float n = tanhf(gin + r*gh[j+256]);
      hsv[j] = (1.f - z)*n + z*hsv[j];
    }
    __syncthreads();
  }
  if (j < 128) vh[(run*16 + b)*D_ + j] = hsv[j];
}

// =====================================================================
// head: out[b][o] = bp[o] + sum_c relu(pe[b][c]) * Wp[o][c]
// =====================================================================
__global__ __launch_bounds__(256) void k_head(
    const float* __restrict__ vh, const float* __restrict__ Wp,
    const float* __restrict__ bp, float* __restrict__ out)
{
  int idx = blockIdx.x*256 + threadIdx.x;
  if (idx >= OUT_*16) return;
  int o = idx >> 4, b = idx & 15;
  const int a1[7] = {0,1,2,3,4,8,9};
  const int a2[7] = {-1,5,6,7,-1,-1,-1};
  float acc = bp[o];
  for (int s = 0; s < 7; ++s) {
    const float* v1 = vh + (a1[s]*16 + b)*D_;
    const float* v2 = (a2[s] >= 0) ? (vh + (a2[s]*16 + b)*D_) : nullptr;
    const float* w = Wp + o*896 + s*D_;
    #pragma unroll 4
    for (int d2 = 0; d2 < D_; ++d2) {
      float v = v1[d2] + (v2 ? v2[d2] : 0.f);
      v = v > 0.f ? v : 0.f;
      acc += v * w[d2];
    }
  }
  out[b*OUT_ + o] = acc;
}

// =====================================================================
extern "C" void kernel_launch(void* const* d_in, const int* in_sizes, int n_in,
                              void* d_out, int out_size, void* d_ws, size_t ws_size,
                              hipStream_t stream)
{
  (void)in_sizes; (void)n_in; (void)out_size; (void)ws_size;
  const int*   cc   = (const int*)  d_in[0];
  const int*   cp   = (const int*)  d_in[1];
  const int*   cd   = (const int*)  d_in[2];
  const int*   cli  = (const int*)  d_in[3];
  const int*   clv  = (const int*)  d_in[4];
  const int*   cii  = (const int*)  d_in[5];
  const int*   civ  = (const int*)  d_in[6];
  const float* wgt  = (const float*)d_in[7];
  const float* age  = (const float*)d_in[8];
  const float* ec   = (const float*)d_in[9];
  const float* ep   = (const float*)d_in[10];
  const float* ed   = (const float*)d_in[11];
  const float* eli  = (const float*)d_in[12];
  const float* elv  = (const float*)d_in[13];
  const float* eii  = (const float*)d_in[14];
  const float* eiv  = (const float*)d_in[15];
  const float* mWih = (const float*)d_in[16];
  const float* mWhh = (const float*)d_in[17];
  const float* mbih = (const float*)d_in[18];
  const float* mbhh = (const float*)d_in[19];
  const float* vWih = (const float*)d_in[20];
  const float* vWhh = (const float*)d_in[21];
  const float* vbih = (const float*)d_in[22];
  const float* vbhh = (const float*)d_in[23];
  const float* Wself= (const float*)d_in[24];
  const float* Wmsg = (const float*)d_in[25];
  const float* fwW  = (const float*)d_in[26];
  const float* fwB  = (const float*)d_in[27];
  const float* faW  = (const float*)d_in[28];
  const float* faB  = (const float*)d_in[29];
  const float* Wp   = (const float*)d_in[30];
  const float* bp   = (const float*)d_in[31];
  float* out = (float*)d_out;
  float* ws  = (float*)d_ws;

  float* vis   = ws + OFF_VIS;
  float* mon   = ws + OFF_MON;
  float* w12   = ws + OFF_W12;
  float* wihTm = ws + OFF_WIHTM;
  float* wihTv = ws + OFF_WIHTV;
  float* xe    = ws + OFF_XE;
  float* gnn   = ws + OFF_GNN;
  float* gi    = ws + OFF_GI;
  float* last  = ws + OFF_LAST;
  float* vgi   = ws + OFF_VGI;
  float* vh    = ws + OFF_VH;

  k_prep<<<2496, 256, 0, stream>>>(Wself, Wmsg, mWih, vWih, wgt, age,
                                   fwW, fwB, faW, faB, w12, wihTm, wihTv, xe);
  k_vis <<<768, 128, 0, stream>>>(cc, cp, cd, ec, ep, ed, vis);
  k_mon <<<16384, 128, 0, stream>>>(cli, clv, cii, civ, eli, elv, eii, eiv, mon);
  k_gnn <<<512, 256, 0, stream>>>(vis, mon, w12, gnn);
  k_gi  <<<1536, 256, 0, stream>>>(gnn, wihTm, mbih, gi);
  k_mgru<<<256, 384, 0, stream>>>(gi, mWhh, mbhh, last);
  k_vgi <<<320, 384, 0, stream>>>(last, xe, wihTv, vbih, vgi);
  k_vgru<<<160, 384, 0, stream>>>(vgi, vWhh, vbhh, vh);
  k_head<<<38, 256, 0, stream>>>(vh, Wp, bp, out);
}